// Round 6
// baseline (478.664 us; speedup 1.0000x reference)
//
#include <hip/hip_runtime.h>

#define NB 4
#define SLQ 256
#define SLK 256
#define DD 768

// tanh(x) = 1 - 2/(1+e^{2x});  e^{2(q+k)} = exp2(q*2log2e)*exp2(k*2log2e).
// Softmax-invariant constants (sum Ws + bs) dropped from the logits.
#define TWO_LOG2E 2.8853900817779268f
#define LOG2E 1.4426950408889634f

typedef _Float16 f16x4 __attribute__((ext_vector_type(4)));
typedef _Float16 f16x8 __attribute__((ext_vector_type(8)));
typedef float f32x4 __attribute__((ext_vector_type(4)));

__device__ __forceinline__ float fexp2(float x) { return __builtin_amdgcn_exp2f(x); }
__device__ __forceinline__ float frcp(float x) { return __builtin_amdgcn_rcpf(x); }

#define LSTR 40            // LDS row stride (halves) for MFMA tiles
#define TSTR 72            // LDS row stride (halves) for epilogue transpose (144B, 16B-aligned)
#define NPS  ((size_t)NB * SLQ * SLK)   // elements per scores-partial slice

// ---------------- Prep 1: q/k/v fp32 -> fp16 ----------------
__global__ __launch_bounds__(256) void prep_a_kernel(
    const float* __restrict__ q, const float* __restrict__ k,
    const float* __restrict__ v, _Float16* __restrict__ qh,
    _Float16* __restrict__ kh, _Float16* __restrict__ vh)
{
    const int z = blockIdx.z;
    const float* src = (z == 0) ? q : (z == 1) ? k : v;
    _Float16* dst = (z == 0) ? qh : (z == 1) ? kh : vh;
    const int i8 = (blockIdx.x * 256 + threadIdx.x) * 8;
    float4 a = *(const float4*)&src[i8];
    float4 b = *(const float4*)&src[i8 + 4];
    f16x8 h;
    h[0] = (_Float16)a.x; h[1] = (_Float16)a.y; h[2] = (_Float16)a.z; h[3] = (_Float16)a.w;
    h[4] = (_Float16)b.x; h[5] = (_Float16)b.y; h[6] = (_Float16)b.z; h[7] = (_Float16)b.w;
    *(f16x8*)&dst[i8] = h;
}

// ---------------- Prep 2: W [in][out] fp32 -> Wt [out][in] fp16 ----------------
__global__ __launch_bounds__(256) void prep_wt_kernel(
    const float* __restrict__ Wq, const float* __restrict__ Wk,
    const float* __restrict__ Wv, _Float16* __restrict__ wtq,
    _Float16* __restrict__ wtk, _Float16* __restrict__ wtv)
{
    const int z = blockIdx.z;
    const float* W = (z == 0) ? Wq : (z == 1) ? Wk : Wv;
    _Float16* Wt = (z == 0) ? wtq : (z == 1) ? wtk : wtv;

    __shared__ float t[64][65];
    const int tid = threadIdx.x;
    const int kt0 = blockIdx.y * 64;
    const int nt0 = blockIdx.x * 64;

    const int col4 = (tid & 15) << 2;
#pragma unroll
    for (int i = 0; i < 4; ++i) {
        const int row = ((tid >> 4) << 2) + i;
        *(float4*)&t[row][col4] = *(const float4*)&W[(size_t)(kt0 + row) * DD + nt0 + col4];
    }
    __syncthreads();
    const int n = tid >> 2;
    const int k16 = (tid & 3) << 4;
    f16x8 h0, h1;
#pragma unroll
    for (int j = 0; j < 8; ++j) {
        h0[j] = (_Float16)t[k16 + j][n];
        h1[j] = (_Float16)t[k16 + 8 + j][n];
    }
    *(f16x8*)&Wt[(size_t)(nt0 + n) * DD + kt0 + k16] = h0;
    *(f16x8*)&Wt[(size_t)(nt0 + n) * DD + kt0 + k16 + 8] = h1;
}

// ---------------- QKV projection, fp16 MFMA, double-buffered LDS ----------------
// z=0 -> eq f32 = exp2(q*2log2e)  [row-major]
// z=1 -> ekc f16 = exp2(k*2log2e) [chunked: [b][d/8][k][8] for coalesced scores reads]
// z=2 -> vsht f16 = v^T            [b][col][k], written via LDS transpose
__global__ __launch_bounds__(256) void qkv_f16_kernel(
    const _Float16* __restrict__ qh, const _Float16* __restrict__ kh,
    const _Float16* __restrict__ vh, const _Float16* __restrict__ wtq,
    const _Float16* __restrict__ wtk, const _Float16* __restrict__ wtv,
    const float* __restrict__ bq, const float* __restrict__ bk,
    const float* __restrict__ bv, float* __restrict__ eq,
    _Float16* __restrict__ ekc, _Float16* __restrict__ vsht)
{
    const int z = blockIdx.z;
    const _Float16* A = (z == 0) ? qh : (z == 1) ? kh : vh;
    const _Float16* Wt = (z == 0) ? wtq : (z == 1) ? wtk : wtv;
    const float* bias = (z == 0) ? bq : (z == 1) ? bk : bv;

    __shared__ _Float16 Sh[2][2][64 * LSTR];   // [buf][A/B] 20480 B

    const int tid = threadIdx.x;
    const int lane = tid & 63;
    const int wid = tid >> 6;
    const int wr = wid >> 1;
    const int wc = wid & 1;
    const int row0 = blockIdx.y * 64;
    const int col0 = blockIdx.x * 64;

    const int sr = tid >> 2;
    const int sc = (tid & 3) << 3;

    const _Float16* Ap = A + (size_t)(row0 + sr) * DD + sc;
    const _Float16* Bp = Wt + (size_t)(col0 + sr) * DD + sc;

    f16x8 pa = *(const f16x8*)Ap;
    f16x8 pb = *(const f16x8*)Bp;

    f32x4 acc[2][2] = {};
    const int kj = (lane >> 4) << 3;
    const int fr = lane & 15;

    *(f16x8*)&Sh[0][0][sr * LSTR + sc] = pa;
    *(f16x8*)&Sh[0][1][sr * LSTR + sc] = pb;
    __syncthreads();

    int p = 0;
    for (int s = 0; s < DD / 32; ++s) {
        if (s + 1 < DD / 32) {
            pa = *(const f16x8*)(Ap + (s + 1) * 32);
            pb = *(const f16x8*)(Bp + (s + 1) * 32);
        }
        f16x8 af0 = *(const f16x8*)&Sh[p][0][(wr * 32 + fr) * LSTR + kj];
        f16x8 af1 = *(const f16x8*)&Sh[p][0][(wr * 32 + 16 + fr) * LSTR + kj];
        f16x8 bf0 = *(const f16x8*)&Sh[p][1][(wc * 32 + fr) * LSTR + kj];
        f16x8 bf1 = *(const f16x8*)&Sh[p][1][(wc * 32 + 16 + fr) * LSTR + kj];
        acc[0][0] = __builtin_amdgcn_mfma_f32_16x16x32_f16(af0, bf0, acc[0][0], 0, 0, 0);
        acc[0][1] = __builtin_amdgcn_mfma_f32_16x16x32_f16(af0, bf1, acc[0][1], 0, 0, 0);
        acc[1][0] = __builtin_amdgcn_mfma_f32_16x16x32_f16(af1, bf0, acc[1][0], 0, 0, 0);
        acc[1][1] = __builtin_amdgcn_mfma_f32_16x16x32_f16(af1, bf1, acc[1][1], 0, 0, 0);
        if (s + 1 < DD / 32) {
            *(f16x8*)&Sh[p ^ 1][0][sr * LSTR + sc] = pa;
            *(f16x8*)&Sh[p ^ 1][1][sr * LSTR + sc] = pb;
        }
        __syncthreads();
        p ^= 1;
    }

    // C/D layout: col = lane&15, row = (lane>>4)*4 + reg [m89 verified]
    const int colb = col0 + wc * 32 + fr;
    const int rowb = row0 + wr * 32 + ((lane >> 4) << 2);

    if (z < 2) {
#pragma unroll
        for (int mf = 0; mf < 2; ++mf) {
#pragma unroll
            for (int nf = 0; nf < 2; ++nf) {
                const int col = colb + nf * 16;
                const float bvv = bias[col];
#pragma unroll
                for (int r = 0; r < 4; ++r) {
                    const int row = rowb + mf * 16 + r;
                    const float arg = fminf((acc[mf][nf][r] + bvv) * TWO_LOG2E, 15.0f);
                    if (z == 0) {
                        eq[(size_t)row * DD + col] = fexp2(arg);
                    } else {
                        const int b = row >> 8, k = row & 255;
                        ekc[(size_t)b * (SLK * DD) + ((col >> 3) * (SLK * 8)) +
                            k * 8 + (col & 7)] = (_Float16)fexp2(arg);
                    }
                }
            }
        }
    } else {
        // stage C^T in LDS, then coalesced f16x8 stores to vsht[b][col][k]
        _Float16* T = (_Float16*)Sh;   // 64 cols x TSTR
#pragma unroll
        for (int mf = 0; mf < 2; ++mf) {
#pragma unroll
            for (int nf = 0; nf < 2; ++nf) {
                const int cl = wc * 32 + fr + nf * 16;
                const float bvv = bias[col0 + cl];
                const int rl = wr * 32 + mf * 16 + ((lane >> 4) << 2);
                f16x4 h;
#pragma unroll
                for (int r = 0; r < 4; ++r) h[r] = (_Float16)(acc[mf][nf][r] + bvv);
                *(f16x4*)&T[cl * TSTR + rl] = h;
            }
        }
        __syncthreads();
        const int b = row0 >> 8;
        const int krow0 = row0 & 255;
#pragma unroll
        for (int j = 0; j < 2; ++j) {
            const int u = tid + 256 * j;
            const int c2 = u >> 3;
            const int g = u & 7;
            f16x8 hv = *(const f16x8*)&T[c2 * TSTR + g * 8];
            *(f16x8*)&vsht[((size_t)b * DD + col0 + c2) * SLK + krow0 + g * 8] = hv;
        }
    }
}

// ---------------- Scores partial (d-split S=4, 2 q-rows/thread) ----------------
// pbuf[s][b][q][k] = -2 * sum_{d in slice s} Ws_d * rcp(1 + Eq[q,d]*Ek[k,d])
__global__ __launch_bounds__(256, 6) void scores_partial_kernel(
    const float* __restrict__ Eq, const _Float16* __restrict__ Ekc,
    const float* __restrict__ Ws, float* __restrict__ pbuf)
{
    const int bz = blockIdx.z;
    const int b = bz >> 2;
    const int s = bz & 3;
    const int k0 = blockIdx.x * 64;
    const int q0 = blockIdx.y * 8;
    const int lane = threadIdx.x & 63;
    const int wid = __builtin_amdgcn_readfirstlane((int)(threadIdx.x >> 6));
    const int q = q0 + (wid << 1);
    const int d0 = s * 192;

    const _Float16* kr = Ekc + (size_t)b * (SLK * DD) + ((d0 >> 3) * (SLK * 8)) +
                         (k0 + lane) * 8;
    const float* qp0 = Eq + (size_t)(b * SLQ + q) * DD + d0;
    const float* qp1 = qp0 + DD;
    const float* wp = Ws + d0;

    float acc0 = 0.f, acc1 = 0.f;

    f16x8 e[2];
    float g0[2][8], g1[2][8], w[2][8];
    e[0] = *(const f16x8*)kr;
#pragma unroll
    for (int j = 0; j < 8; ++j) { g0[0][j] = qp0[j]; g1[0][j] = qp1[j]; w[0][j] = wp[j]; }

#pragma unroll
    for (int c = 0; c < 24; ++c) {
        const int cur = c & 1, nxt = cur ^ 1;
        if (c + 1 < 24) {
            e[nxt] = *(const f16x8*)(kr + (size_t)(c + 1) * (SLK * 8));
            const int dn = (c + 1) * 8;
#pragma unroll
            for (int j = 0; j < 8; ++j) {
                g0[nxt][j] = qp0[dn + j]; g1[nxt][j] = qp1[dn + j]; w[nxt][j] = wp[dn + j];
            }
        }
#pragma unroll
        for (int j = 0; j < 8; ++j) {
            const float ea = (float)e[cur][j];
            acc0 = fmaf(w[cur][j], frcp(fmaf(g0[cur][j], ea, 1.0f)), acc0);
            acc1 = fmaf(w[cur][j], frcp(fmaf(g1[cur][j], ea, 1.0f)), acc1);
        }
    }

    const size_t o = (size_t)s * NPS + (size_t)(b * SLQ + q) * SLK + k0 + lane;
    pbuf[o] = -2.0f * acc0;
    pbuf[o + SLK] = -2.0f * acc1;
}

// ---------------- Combine partials + softmax (one wave per row) ----------------
__global__ __launch_bounds__(256) void softmax_combine_kernel(
    const float* __restrict__ pbuf, float* __restrict__ attnw,
    _Float16* __restrict__ phalf)
{
    const int lane = threadIdx.x & 63;
    const int wv = threadIdx.x >> 6;
    const int row = blockIdx.x * 4 + wv;     // 0..1023
    const size_t base = (size_t)row * SLK + (lane << 2);

    float4 x0 = *(const float4*)&pbuf[base];
    float4 x1 = *(const float4*)&pbuf[base + NPS];
    float4 x2 = *(const float4*)&pbuf[base + 2 * NPS];
    float4 x3 = *(const float4*)&pbuf[base + 3 * NPS];
    float4 x;
    x.x = (x0.x + x1.x) + (x2.x + x3.x);
    x.y = (x0.y + x1.y) + (x2.y + x3.y);
    x.z = (x0.z + x1.z) + (x2.z + x3.z);
    x.w = (x0.w + x1.w) + (x2.w + x3.w);

    float m = fmaxf(fmaxf(x.x, x.y), fmaxf(x.z, x.w));
#pragma unroll
    for (int off = 32; off; off >>= 1) m = fmaxf(m, __shfl_xor(m, off, 64));

    float e0 = fexp2((x.x - m) * LOG2E);
    float e1 = fexp2((x.y - m) * LOG2E);
    float e2 = fexp2((x.z - m) * LOG2E);
    float e3 = fexp2((x.w - m) * LOG2E);
    float sm = (e0 + e1) + (e2 + e3);
#pragma unroll
    for (int off = 32; off; off >>= 1) sm += __shfl_xor(sm, off, 64);

    const float inv = 1.0f / sm;
    float4 o;
    o.x = e0 * inv; o.y = e1 * inv; o.z = e2 * inv; o.w = e3 * inv;
    *(float4*)&attnw[base] = o;

    f16x4 h;
    h[0] = (_Float16)o.x; h[1] = (_Float16)o.y;
    h[2] = (_Float16)o.z; h[3] = (_Float16)o.w;
    *(f16x4*)&phalf[base] = h;
}

// ---------------- Attended: out = P @ V, fp16 MFMA, double-buffered ----------------
__global__ __launch_bounds__(256) void attended_f16_kernel(
    const _Float16* __restrict__ phalf, const _Float16* __restrict__ vsht,
    float* __restrict__ out)
{
    const int b = blockIdx.z;
    const _Float16* A = phalf + (size_t)b * SLQ * SLK;
    const _Float16* Bt = vsht + (size_t)b * DD * SLK;
    float* C = out + (size_t)b * SLQ * DD;

    __shared__ _Float16 Sh[2][2][64 * LSTR];

    const int tid = threadIdx.x;
    const int lane = tid & 63;
    const int wid = tid >> 6;
    const int wr = wid >> 1;
    const int wc = wid & 1;
    const int row0 = blockIdx.y * 64;
    const int col0 = blockIdx.x * 64;

    const int sr = tid >> 2;
    const int sc = (tid & 3) << 3;

    const _Float16* Ap = A + (size_t)(row0 + sr) * SLK + sc;
    const _Float16* Bp = Bt + (size_t)(col0 + sr) * SLK + sc;

    f16x8 pa = *(const f16x8*)Ap;
    f16x8 pb = *(const f16x8*)Bp;

    f32x4 acc[2][2] = {};
    const int kj = (lane >> 4) << 3;
    const int fr = lane & 15;

    *(f16x8*)&Sh[0][0][sr * LSTR + sc] = pa;
    *(f16x8*)&Sh[0][1][sr * LSTR + sc] = pb;
    __syncthreads();

    int p = 0;
    for (int s = 0; s < SLK / 32; ++s) {
        if (s + 1 < SLK / 32) {
            pa = *(const f16x8*)(Ap + (s + 1) * 32);
            pb = *(const f16x8*)(Bp + (s + 1) * 32);
        }
        f16x8 af0 = *(const f16x8*)&Sh[p][0][(wr * 32 + fr) * LSTR + kj];
        f16x8 af1 = *(const f16x8*)&Sh[p][0][(wr * 32 + 16 + fr) * LSTR + kj];
        f16x8 bf0 = *(const f16x8*)&Sh[p][1][(wc * 32 + fr) * LSTR + kj];
        f16x8 bf1 = *(const f16x8*)&Sh[p][1][(wc * 32 + 16 + fr) * LSTR + kj];
        acc[0][0] = __builtin_amdgcn_mfma_f32_16x16x32_f16(af0, bf0, acc[0][0], 0, 0, 0);
        acc[0][1] = __builtin_amdgcn_mfma_f32_16x16x32_f16(af0, bf1, acc[0][1], 0, 0, 0);
        acc[1][0] = __builtin_amdgcn_mfma_f32_16x16x32_f16(af1, bf0, acc[1][0], 0, 0, 0);
        acc[1][1] = __builtin_amdgcn_mfma_f32_16x16x32_f16(af1, bf1, acc[1][1], 0, 0, 0);
        if (s + 1 < SLK / 32) {
            *(f16x8*)&Sh[p ^ 1][0][sr * LSTR + sc] = pa;
            *(f16x8*)&Sh[p ^ 1][1][sr * LSTR + sc] = pb;
        }
        __syncthreads();
        p ^= 1;
    }

    const int colb = col0 + wc * 32 + fr;
    const int rowb = row0 + wr * 32 + ((lane >> 4) << 2);
#pragma unroll
    for (int mf = 0; mf < 2; ++mf)
#pragma unroll
        for (int nf = 0; nf < 2; ++nf)
#pragma unroll
            for (int r = 0; r < 4; ++r)
                C[(size_t)(rowb + mf * 16 + r) * DD + colb + nf * 16] = acc[mf][nf][r];
}

extern "C" void kernel_launch(void* const* d_in, const int* in_sizes, int n_in,
                              void* d_out, int out_size, void* d_ws, size_t ws_size,
                              hipStream_t stream)
{
    (void)in_sizes; (void)n_in; (void)out_size; (void)ws_size;

    const float* query = (const float*)d_in[0];
    const float* key   = (const float*)d_in[1];
    const float* value = (const float*)d_in[2];
    const float* Wq = (const float*)d_in[3];
    const float* bq = (const float*)d_in[4];
    const float* Wk = (const float*)d_in[5];
    const float* bk = (const float*)d_in[6];
    const float* Wv = (const float*)d_in[7];
    const float* bv = (const float*)d_in[8];
    const float* Ws = (const float*)d_in[9];
    // d_in[10] (bs): softmax-invariant shift, unused.

    const size_t NE = (size_t)NB * SLQ * DD;   // 786432
    const size_t NW = (size_t)DD * DD;         // 589824

    char* w = (char*)d_ws;
    float* eq = (float*)w;               w += NE * 4;
    _Float16* ekc = (_Float16*)w;        w += NE * 2;
    _Float16* vsht = (_Float16*)w;       w += NE * 2;
    _Float16* phalf = (_Float16*)w;      w += NPS * 2;
    _Float16* qh = (_Float16*)w;         w += NE * 2;
    _Float16* kh = (_Float16*)w;         w += NE * 2;
    _Float16* vh = (_Float16*)w;         w += NE * 2;
    _Float16* wtq = (_Float16*)w;        w += NW * 2;
    _Float16* wtk = (_Float16*)w;        w += NW * 2;
    _Float16* wtv = (_Float16*)w;        w += NW * 2;
    float* pbuf = (float*)w;             // 4 * NPS f32 = 4 MB

    float* out = (float*)d_out;
    float* attended = out;               // [4,256,768]
    float* attnw = out + NE;             // [4,256,256]

    prep_a_kernel<<<dim3(NE / (256 * 8), 1, 3), 256, 0, stream>>>(
        query, key, value, qh, kh, vh);
    prep_wt_kernel<<<dim3(DD / 64, DD / 64, 3), 256, 0, stream>>>(
        Wq, Wk, Wv, wtq, wtk, wtv);
    qkv_f16_kernel<<<dim3(DD / 64, (NB * SLQ) / 64, 3), 256, 0, stream>>>(
        qh, kh, vh, wtq, wtk, wtv, bq, bk, bv, eq, ekc, vsht);
    scores_partial_kernel<<<dim3(SLK / 64, SLQ / 8, NB * 4), 256, 0, stream>>>(
        eq, ekc, Ws, pbuf);
    softmax_combine_kernel<<<dim3((NB * SLQ) / 4), 256, 0, stream>>>(
        pbuf, attnw, phalf);
    attended_f16_kernel<<<dim3(DD / 64, SLQ / 64, NB), 256, 0, stream>>>(
        phalf, vsht, attended);
}

// Round 8
// 133.020 us; speedup vs baseline: 3.5984x; 3.5984x over previous
//
#include <hip/hip_runtime.h>

#define NB 4
#define SLQ 256
#define SLK 256
#define DD 768

// tanh(x) = 1 - 2/(1+e^{2x});  e^{2(q+k)} = exp2(q*2log2e)*exp2(k*2log2e).
// Softmax-invariant constants (sum Ws + bs) dropped from the logits.
#define TWO_LOG2E 2.8853900817779268f
#define LOG2E 1.4426950408889634f

typedef _Float16 f16x4 __attribute__((ext_vector_type(4)));
typedef _Float16 f16x8 __attribute__((ext_vector_type(8)));
typedef float f32x4 __attribute__((ext_vector_type(4)));

__device__ __forceinline__ float fexp2(float x) { return __builtin_amdgcn_exp2f(x); }
__device__ __forceinline__ float frcp(float x) { return __builtin_amdgcn_rcpf(x); }

#define LSTR 40            // LDS row stride (halves) for MFMA tiles
#define TSTR 72            // LDS row stride (halves) for epilogue transpose
#define NPS  ((size_t)NB * SLQ * SLK)   // elements per scores-partial slice

// ---------------- Prep 1: q/k/v fp32 -> fp16 ----------------
__global__ __launch_bounds__(256) void prep_a_kernel(
    const float* __restrict__ q, const float* __restrict__ k,
    const float* __restrict__ v, _Float16* __restrict__ qh,
    _Float16* __restrict__ kh, _Float16* __restrict__ vh)
{
    const int z = blockIdx.z;
    const float* src = (z == 0) ? q : (z == 1) ? k : v;
    _Float16* dst = (z == 0) ? qh : (z == 1) ? kh : vh;
    const int i8 = (blockIdx.x * 256 + threadIdx.x) * 8;
    float4 a = *(const float4*)&src[i8];
    float4 b = *(const float4*)&src[i8 + 4];
    f16x8 h;
    h[0] = (_Float16)a.x; h[1] = (_Float16)a.y; h[2] = (_Float16)a.z; h[3] = (_Float16)a.w;
    h[4] = (_Float16)b.x; h[5] = (_Float16)b.y; h[6] = (_Float16)b.z; h[7] = (_Float16)b.w;
    *(f16x8*)&dst[i8] = h;
}

// ---------------- Prep 2: W [in][out] fp32 -> Wt [out][in] fp16 ----------------
__global__ __launch_bounds__(256) void prep_wt_kernel(
    const float* __restrict__ Wq, const float* __restrict__ Wk,
    const float* __restrict__ Wv, _Float16* __restrict__ wtq,
    _Float16* __restrict__ wtk, _Float16* __restrict__ wtv)
{
    const int z = blockIdx.z;
    const float* W = (z == 0) ? Wq : (z == 1) ? Wk : Wv;
    _Float16* Wt = (z == 0) ? wtq : (z == 1) ? wtk : wtv;

    __shared__ float t[64][65];
    const int tid = threadIdx.x;
    const int kt0 = blockIdx.y * 64;
    const int nt0 = blockIdx.x * 64;

    const int col4 = (tid & 15) << 2;
#pragma unroll
    for (int i = 0; i < 4; ++i) {
        const int row = ((tid >> 4) << 2) + i;
        *(float4*)&t[row][col4] = *(const float4*)&W[(size_t)(kt0 + row) * DD + nt0 + col4];
    }
    __syncthreads();
    const int n = tid >> 2;
    const int k16 = (tid & 3) << 4;
    f16x8 h0, h1;
#pragma unroll
    for (int j = 0; j < 8; ++j) {
        h0[j] = (_Float16)t[k16 + j][n];
        h1[j] = (_Float16)t[k16 + 8 + j][n];
    }
    *(f16x8*)&Wt[(size_t)(nt0 + n) * DD + kt0 + k16] = h0;
    *(f16x8*)&Wt[(size_t)(nt0 + n) * DD + kt0 + k16 + 8] = h1;
}

// ---------------- QKV projection, fp16 MFMA, double-buffered LDS ----------------
// z=0 -> eq f32 = exp2(q*2log2e)  [row-major]
// z=1 -> ekc f16 = exp2(k*2log2e) [chunked: [b][d/8][k][8] for coalesced scores reads]
// z=2 -> vsht f16 = v^T            [b][col][k], written via LDS transpose
__global__ __launch_bounds__(256) void qkv_f16_kernel(
    const _Float16* __restrict__ qh, const _Float16* __restrict__ kh,
    const _Float16* __restrict__ vh, const _Float16* __restrict__ wtq,
    const _Float16* __restrict__ wtk, const _Float16* __restrict__ wtv,
    const float* __restrict__ bq, const float* __restrict__ bk,
    const float* __restrict__ bv, float* __restrict__ eq,
    _Float16* __restrict__ ekc, _Float16* __restrict__ vsht)
{
    const int z = blockIdx.z;
    const _Float16* A = (z == 0) ? qh : (z == 1) ? kh : vh;
    const _Float16* Wt = (z == 0) ? wtq : (z == 1) ? wtk : wtv;
    const float* bias = (z == 0) ? bq : (z == 1) ? bk : bv;

    __shared__ _Float16 Sh[2][2][64 * LSTR];   // [buf][A/B] 20480 B

    const int tid = threadIdx.x;
    const int lane = tid & 63;
    const int wid = tid >> 6;
    const int wr = wid >> 1;
    const int wc = wid & 1;
    const int row0 = blockIdx.y * 64;
    const int col0 = blockIdx.x * 64;

    const int sr = tid >> 2;
    const int sc = (tid & 3) << 3;

    const _Float16* Ap = A + (size_t)(row0 + sr) * DD + sc;
    const _Float16* Bp = Wt + (size_t)(col0 + sr) * DD + sc;

    f16x8 pa = *(const f16x8*)Ap;
    f16x8 pb = *(const f16x8*)Bp;

    f32x4 acc[2][2] = {};
    const int kj = (lane >> 4) << 3;
    const int fr = lane & 15;

    *(f16x8*)&Sh[0][0][sr * LSTR + sc] = pa;
    *(f16x8*)&Sh[0][1][sr * LSTR + sc] = pb;
    __syncthreads();

    int p = 0;
    for (int s = 0; s < DD / 32; ++s) {
        if (s + 1 < DD / 32) {
            pa = *(const f16x8*)(Ap + (s + 1) * 32);
            pb = *(const f16x8*)(Bp + (s + 1) * 32);
        }
        f16x8 af0 = *(const f16x8*)&Sh[p][0][(wr * 32 + fr) * LSTR + kj];
        f16x8 af1 = *(const f16x8*)&Sh[p][0][(wr * 32 + 16 + fr) * LSTR + kj];
        f16x8 bf0 = *(const f16x8*)&Sh[p][1][(wc * 32 + fr) * LSTR + kj];
        f16x8 bf1 = *(const f16x8*)&Sh[p][1][(wc * 32 + 16 + fr) * LSTR + kj];
        acc[0][0] = __builtin_amdgcn_mfma_f32_16x16x32_f16(af0, bf0, acc[0][0], 0, 0, 0);
        acc[0][1] = __builtin_amdgcn_mfma_f32_16x16x32_f16(af0, bf1, acc[0][1], 0, 0, 0);
        acc[1][0] = __builtin_amdgcn_mfma_f32_16x16x32_f16(af1, bf0, acc[1][0], 0, 0, 0);
        acc[1][1] = __builtin_amdgcn_mfma_f32_16x16x32_f16(af1, bf1, acc[1][1], 0, 0, 0);
        if (s + 1 < DD / 32) {
            *(f16x8*)&Sh[p ^ 1][0][sr * LSTR + sc] = pa;
            *(f16x8*)&Sh[p ^ 1][1][sr * LSTR + sc] = pb;
        }
        __syncthreads();
        p ^= 1;
    }

    // C/D layout: col = lane&15, row = (lane>>4)*4 + reg [m89 verified]
    const int colb = col0 + wc * 32 + fr;
    const int rowb = row0 + wr * 32 + ((lane >> 4) << 2);

    if (z < 2) {
#pragma unroll
        for (int mf = 0; mf < 2; ++mf) {
#pragma unroll
            for (int nf = 0; nf < 2; ++nf) {
                const int col = colb + nf * 16;
                const float bvv = bias[col];
#pragma unroll
                for (int r = 0; r < 4; ++r) {
                    const int row = rowb + mf * 16 + r;
                    const float arg = fminf((acc[mf][nf][r] + bvv) * TWO_LOG2E, 15.0f);
                    if (z == 0) {
                        eq[(size_t)row * DD + col] = fexp2(arg);
                    } else {
                        const int b = row >> 8, k = row & 255;
                        ekc[(size_t)b * (SLK * DD) + ((col >> 3) * (SLK * 8)) +
                            k * 8 + (col & 7)] = (_Float16)fexp2(arg);
                    }
                }
            }
        }
    } else {
        // stage C^T in LDS, then coalesced f16x8 stores to vsht[b][col][k]
        _Float16* T = (_Float16*)Sh;   // 64 cols x TSTR
#pragma unroll
        for (int mf = 0; mf < 2; ++mf) {
#pragma unroll
            for (int nf = 0; nf < 2; ++nf) {
                const int cl = wc * 32 + fr + nf * 16;
                const float bvv = bias[col0 + cl];
                const int rl = wr * 32 + mf * 16 + ((lane >> 4) << 2);
                f16x4 h;
#pragma unroll
                for (int r = 0; r < 4; ++r) h[r] = (_Float16)(acc[mf][nf][r] + bvv);
                *(f16x4*)&T[cl * TSTR + rl] = h;
            }
        }
        __syncthreads();
        const int b = row0 >> 8;
        const int krow0 = row0 & 255;
#pragma unroll
        for (int j = 0; j < 2; ++j) {
            const int u = tid + 256 * j;
            const int c2 = u >> 3;
            const int g = u & 7;
            f16x8 hv = *(const f16x8*)&T[c2 * TSTR + g * 8];
            *(f16x8*)&vsht[((size_t)b * DD + col0 + c2) * SLK + krow0 + g * 8] = hv;
        }
    }
}

// ---------------- Scores partial (d-split S=4, 2 q-rows/thread) ----------------
// pbuf[s][b][q][k] = -2 * sum_{d in slice s} Ws_d * rcp(1 + Eq[q,d]*Ek[k,d])
// Straight loop, named vector vars only (NO runtime-indexed arrays -> no scratch).
__global__ __launch_bounds__(256) void scores_partial_kernel(
    const float* __restrict__ Eq, const _Float16* __restrict__ Ekc,
    const float* __restrict__ Ws, float* __restrict__ pbuf)
{
    const int bz = blockIdx.z;
    const int b = bz >> 2;
    const int s = bz & 3;
    const int k0 = blockIdx.x * 64;
    const int q0 = blockIdx.y * 8;
    const int lane = threadIdx.x & 63;
    const int wid = __builtin_amdgcn_readfirstlane((int)(threadIdx.x >> 6));
    const int q = q0 + (wid << 1);
    const int d0 = s * 192;

    const _Float16* kr = Ekc + (size_t)b * (SLK * DD) + ((d0 >> 3) * (SLK * 8)) +
                         (k0 + lane) * 8;
    const float* qp0 = Eq + (size_t)(b * SLQ + q) * DD + d0;   // wave-uniform
    const float* qp1 = qp0 + DD;                               // wave-uniform
    const float* wp = Ws + d0;                                 // grid-uniform

    float acc0 = 0.f, acc1 = 0.f;

#pragma unroll 4
    for (int c = 0; c < 24; ++c) {
        const int dn = c * 8;
        f16x8 e = *(const f16x8*)(kr + (size_t)c * (SLK * 8));
        float4 ga0 = *(const float4*)(qp0 + dn);
        float4 ga1 = *(const float4*)(qp0 + dn + 4);
        float4 gb0 = *(const float4*)(qp1 + dn);
        float4 gb1 = *(const float4*)(qp1 + dn + 4);
        float4 w0 = *(const float4*)(wp + dn);
        float4 w1 = *(const float4*)(wp + dn + 4);

        float e0 = (float)e[0], e1 = (float)e[1], e2 = (float)e[2], e3 = (float)e[3];
        float e4 = (float)e[4], e5 = (float)e[5], e6 = (float)e[6], e7 = (float)e[7];

        acc0 = fmaf(w0.x, frcp(fmaf(ga0.x, e0, 1.0f)), acc0);
        acc1 = fmaf(w0.x, frcp(fmaf(gb0.x, e0, 1.0f)), acc1);
        acc0 = fmaf(w0.y, frcp(fmaf(ga0.y, e1, 1.0f)), acc0);
        acc1 = fmaf(w0.y, frcp(fmaf(gb0.y, e1, 1.0f)), acc1);
        acc0 = fmaf(w0.z, frcp(fmaf(ga0.z, e2, 1.0f)), acc0);
        acc1 = fmaf(w0.z, frcp(fmaf(gb0.z, e2, 1.0f)), acc1);
        acc0 = fmaf(w0.w, frcp(fmaf(ga0.w, e3, 1.0f)), acc0);
        acc1 = fmaf(w0.w, frcp(fmaf(gb0.w, e3, 1.0f)), acc1);
        acc0 = fmaf(w1.x, frcp(fmaf(ga1.x, e4, 1.0f)), acc0);
        acc1 = fmaf(w1.x, frcp(fmaf(gb1.x, e4, 1.0f)), acc1);
        acc0 = fmaf(w1.y, frcp(fmaf(ga1.y, e5, 1.0f)), acc0);
        acc1 = fmaf(w1.y, frcp(fmaf(gb1.y, e5, 1.0f)), acc1);
        acc0 = fmaf(w1.z, frcp(fmaf(ga1.z, e6, 1.0f)), acc0);
        acc1 = fmaf(w1.z, frcp(fmaf(gb1.z, e6, 1.0f)), acc1);
        acc0 = fmaf(w1.w, frcp(fmaf(ga1.w, e7, 1.0f)), acc0);
        acc1 = fmaf(w1.w, frcp(fmaf(gb1.w, e7, 1.0f)), acc1);
    }

    const size_t o = (size_t)s * NPS + (size_t)(b * SLQ + q) * SLK + k0 + lane;
    pbuf[o] = -2.0f * acc0;
    pbuf[o + SLK] = -2.0f * acc1;
}

// ---------------- Combine partials + softmax (one wave per row) ----------------
__global__ __launch_bounds__(256) void softmax_combine_kernel(
    const float* __restrict__ pbuf, float* __restrict__ attnw,
    _Float16* __restrict__ phalf)
{
    const int lane = threadIdx.x & 63;
    const int wv = threadIdx.x >> 6;
    const int row = blockIdx.x * 4 + wv;     // 0..1023
    const size_t base = (size_t)row * SLK + (lane << 2);

    float4 x0 = *(const float4*)&pbuf[base];
    float4 x1 = *(const float4*)&pbuf[base + NPS];
    float4 x2 = *(const float4*)&pbuf[base + 2 * NPS];
    float4 x3 = *(const float4*)&pbuf[base + 3 * NPS];
    float4 x;
    x.x = (x0.x + x1.x) + (x2.x + x3.x);
    x.y = (x0.y + x1.y) + (x2.y + x3.y);
    x.z = (x0.z + x1.z) + (x2.z + x3.z);
    x.w = (x0.w + x1.w) + (x2.w + x3.w);

    float m = fmaxf(fmaxf(x.x, x.y), fmaxf(x.z, x.w));
#pragma unroll
    for (int off = 32; off; off >>= 1) m = fmaxf(m, __shfl_xor(m, off, 64));

    float e0 = fexp2((x.x - m) * LOG2E);
    float e1 = fexp2((x.y - m) * LOG2E);
    float e2 = fexp2((x.z - m) * LOG2E);
    float e3 = fexp2((x.w - m) * LOG2E);
    float sm = (e0 + e1) + (e2 + e3);
#pragma unroll
    for (int off = 32; off; off >>= 1) sm += __shfl_xor(sm, off, 64);

    const float inv = 1.0f / sm;
    float4 o;
    o.x = e0 * inv; o.y = e1 * inv; o.z = e2 * inv; o.w = e3 * inv;
    *(float4*)&attnw[base] = o;

    f16x4 h;
    h[0] = (_Float16)o.x; h[1] = (_Float16)o.y;
    h[2] = (_Float16)o.z; h[3] = (_Float16)o.w;
    *(f16x4*)&phalf[base] = h;
}

// ---------------- Attended: out = P @ V, fp16 MFMA, double-buffered ----------------
__global__ __launch_bounds__(256) void attended_f16_kernel(
    const _Float16* __restrict__ phalf, const _Float16* __restrict__ vsht,
    float* __restrict__ out)
{
    const int b = blockIdx.z;
    const _Float16* A = phalf + (size_t)b * SLQ * SLK;
    const _Float16* Bt = vsht + (size_t)b * DD * SLK;
    float* C = out + (size_t)b * SLQ * DD;

    __shared__ _Float16 Sh[2][2][64 * LSTR];

    const int tid = threadIdx.x;
    const int lane = tid & 63;
    const int wid = tid >> 6;
    const int wr = wid >> 1;
    const int wc = wid & 1;
    const int row0 = blockIdx.y * 64;
    const int col0 = blockIdx.x * 64;

    const int sr = tid >> 2;
    const int sc = (tid & 3) << 3;

    const _Float16* Ap = A + (size_t)(row0 + sr) * SLK + sc;
    const _Float16* Bp = Bt + (size_t)(col0 + sr) * SLK + sc;

    f16x8 pa = *(const f16x8*)Ap;
    f16x8 pb = *(const f16x8*)Bp;

    f32x4 acc[2][2] = {};
    const int kj = (lane >> 4) << 3;
    const int fr = lane & 15;

    *(f16x8*)&Sh[0][0][sr * LSTR + sc] = pa;
    *(f16x8*)&Sh[0][1][sr * LSTR + sc] = pb;
    __syncthreads();

    int p = 0;
    for (int s = 0; s < SLK / 32; ++s) {
        if (s + 1 < SLK / 32) {
            pa = *(const f16x8*)(Ap + (s + 1) * 32);
            pb = *(const f16x8*)(Bp + (s + 1) * 32);
        }
        f16x8 af0 = *(const f16x8*)&Sh[p][0][(wr * 32 + fr) * LSTR + kj];
        f16x8 af1 = *(const f16x8*)&Sh[p][0][(wr * 32 + 16 + fr) * LSTR + kj];
        f16x8 bf0 = *(const f16x8*)&Sh[p][1][(wc * 32 + fr) * LSTR + kj];
        f16x8 bf1 = *(const f16x8*)&Sh[p][1][(wc * 32 + 16 + fr) * LSTR + kj];
        acc[0][0] = __builtin_amdgcn_mfma_f32_16x16x32_f16(af0, bf0, acc[0][0], 0, 0, 0);
        acc[0][1] = __builtin_amdgcn_mfma_f32_16x16x32_f16(af0, bf1, acc[0][1], 0, 0, 0);
        acc[1][0] = __builtin_amdgcn_mfma_f32_16x16x32_f16(af1, bf0, acc[1][0], 0, 0, 0);
        acc[1][1] = __builtin_amdgcn_mfma_f32_16x16x32_f16(af1, bf1, acc[1][1], 0, 0, 0);
        if (s + 1 < SLK / 32) {
            *(f16x8*)&Sh[p ^ 1][0][sr * LSTR + sc] = pa;
            *(f16x8*)&Sh[p ^ 1][1][sr * LSTR + sc] = pb;
        }
        __syncthreads();
        p ^= 1;
    }

    const int colb = col0 + wc * 32 + fr;
    const int rowb = row0 + wr * 32 + ((lane >> 4) << 2);
#pragma unroll
    for (int mf = 0; mf < 2; ++mf)
#pragma unroll
        for (int nf = 0; nf < 2; ++nf)
#pragma unroll
            for (int r = 0; r < 4; ++r)
                C[(size_t)(rowb + mf * 16 + r) * DD + colb + nf * 16] = acc[mf][nf][r];
}

extern "C" void kernel_launch(void* const* d_in, const int* in_sizes, int n_in,
                              void* d_out, int out_size, void* d_ws, size_t ws_size,
                              hipStream_t stream)
{
    (void)in_sizes; (void)n_in; (void)out_size; (void)ws_size;

    const float* query = (const float*)d_in[0];
    const float* key   = (const float*)d_in[1];
    const float* value = (const float*)d_in[2];
    const float* Wq = (const float*)d_in[3];
    const float* bq = (const float*)d_in[4];
    const float* Wk = (const float*)d_in[5];
    const float* bk = (const float*)d_in[6];
    const float* Wv = (const float*)d_in[7];
    const float* bv = (const float*)d_in[8];
    const float* Ws = (const float*)d_in[9];
    // d_in[10] (bs): softmax-invariant shift, unused.

    const size_t NE = (size_t)NB * SLQ * DD;   // 786432
    const size_t NW = (size_t)DD * DD;         // 589824

    char* w = (char*)d_ws;
    float* eq = (float*)w;               w += NE * 4;
    _Float16* ekc = (_Float16*)w;        w += NE * 2;
    _Float16* vsht = (_Float16*)w;       w += NE * 2;
    _Float16* phalf = (_Float16*)w;      w += NPS * 2;
    _Float16* qh = (_Float16*)w;         w += NE * 2;
    _Float16* kh = (_Float16*)w;         w += NE * 2;
    _Float16* vh = (_Float16*)w;         w += NE * 2;
    _Float16* wtq = (_Float16*)w;        w += NW * 2;
    _Float16* wtk = (_Float16*)w;        w += NW * 2;
    _Float16* wtv = (_Float16*)w;        w += NW * 2;
    float* pbuf = (float*)w;             // 4 * NPS f32 = 4 MB

    float* out = (float*)d_out;
    float* attended = out;               // [4,256,768]
    float* attnw = out + NE;             // [4,256,256]

    prep_a_kernel<<<dim3(NE / (256 * 8), 1, 3), 256, 0, stream>>>(
        query, key, value, qh, kh, vh);
    prep_wt_kernel<<<dim3(DD / 64, DD / 64, 3), 256, 0, stream>>>(
        Wq, Wk, Wv, wtq, wtk, wtv);
    qkv_f16_kernel<<<dim3(DD / 64, (NB * SLQ) / 64, 3), 256, 0, stream>>>(
        qh, kh, vh, wtq, wtk, wtv, bq, bk, bv, eq, ekc, vsht);
    scores_partial_kernel<<<dim3(SLK / 64, SLQ / 8, NB * 4), 256, 0, stream>>>(
        eq, ekc, Ws, pbuf);
    softmax_combine_kernel<<<dim3((NB * SLQ) / 4), 256, 0, stream>>>(
        pbuf, attnw, phalf);
    attended_f16_kernel<<<dim3(DD / 64, SLQ / 64, NB), 256, 0, stream>>>(
        phalf, vsht, attended);
}